// Round 6
// baseline (657.074 us; speedup 1.0000x reference)
//
#include <hip/hip_runtime.h>
#include <math.h>

#define LL 4096
#define NB 64
#define WW 64
#define NMODES 32
#define NCIN 24
#define NLAY 4
#define NPROJ 128
#define NSTC 16
#define NSPLIT 16
#define PK 136   // LDS pitch (bf16) for k_fused B tile

typedef __attribute__((ext_vector_type(8))) short short8;
typedef __attribute__((ext_vector_type(4))) float f32x4;

static __device__ __forceinline__ float gelu_tanh(float x){
    const float c0 = 0.7978845608028654f;   // sqrt(2/pi)
    const float c1 = 0.044715f;
    float t = tanhf(c0*(x + c1*x*x*x));
    return 0.5f*x*(1.0f+t);
}

static __device__ __forceinline__ unsigned short bf16_rn(float v){
    unsigned int u = __float_as_uint(v);
    unsigned int r = (u + 0x7fffu + ((u>>16)&1u)) >> 16;
    return (unsigned short)r;
}
static __device__ __forceinline__ float bf16f(unsigned short h){
    return __uint_as_float(((unsigned int)h)<<16);
}
static __device__ __forceinline__ void split_store(unsigned short* hi, unsigned short* lo,
                                                   size_t idx, float v){
    unsigned short h = bf16_rn(v);
    hi[idx] = h;
    lo[idx] = bf16_rn(v - bf16f(h));
}

// ---------------- tables (bf16 hi/lo planes) ----------------
// TD[n][x], n<32: cos(2pi n x/L); n>=32: -sin. TI: irfft-scaled, row 32 (Im bin0)=0.
__global__ void k_tables(unsigned short* __restrict__ TD_hi, unsigned short* __restrict__ TD_lo,
                         unsigned short* __restrict__ TI_hi, unsigned short* __restrict__ TI_lo){
    int idx = blockIdx.x*256 + threadIdx.x;
    if (idx >= LL*NMODES) return;
    int x = idx & (LL-1);
    int k = idx >> 12;
    int ph = (k*x) & (LL-1);                 // exact integer phase mod L
    float ang = (6.283185307179586f/(float)LL)*(float)ph;
    float c = cosf(ang), s = sinf(ang);
    split_store(TD_hi, TD_lo, (size_t)k*LL + x, c);
    split_store(TD_hi, TD_lo, (size_t)(k+NMODES)*LL + x, -s);
    float tc, ts;
    if (k == 0){ tc = 1.0f/(float)LL; ts = 0.0f; }
    else { tc = (2.0f/(float)LL)*c; ts = -(2.0f/(float)LL)*s; }
    split_store(TI_hi, TI_lo, (size_t)k*LL + x, tc);
    split_store(TI_hi, TI_lo, (size_t)(k+NMODES)*LL + x, ts);
}

// ---------------- weight prep: wrT/wiT fp32 [l][m][i][o]; skwT bf16 [l][o][i] ----------------
__global__ void k_wt(const float* __restrict__ wr, const float* __restrict__ wi,
                     float* __restrict__ wrT, float* __restrict__ wiT,
                     const float* __restrict__ skw,
                     unsigned short* __restrict__ skwT_hi, unsigned short* __restrict__ skwT_lo){
    int idx = blockIdx.x*256 + threadIdx.x;
    if (idx < NLAY*WW*WW*NMODES){
        int m = idx & 31;
        int o = (idx >> 5) & 63;
        int i = (idx >> 11) & 63;
        int l = idx >> 17;
        size_t dst = (((size_t)l*NMODES + m)*WW + i)*WW + o;
        wrT[dst] = wr[idx];
        wiT[dst] = wi[idx];
    }
    if (idx < NLAY*WW*WW){
        int o = idx & 63;
        int i = (idx >> 6) & 63;
        int l = idx >> 12;
        float v = skw[((size_t)l*WW + i)*WW + o];
        split_store(skwT_hi, skwT_lo, ((size_t)l*WW + o)*WW + i, v);
    }
}

// ---------------- lifting -> h planes ----------------
__global__ void k_lift(const float* __restrict__ u, const float* __restrict__ z,
                       const float* __restrict__ w0, const float* __restrict__ b0,
                       unsigned short* __restrict__ h_hi, unsigned short* __restrict__ h_lo){
    __shared__ float Ws[NCIN*WW];
    __shared__ float Bs[WW];
    __shared__ float Zs[16];
    int b = blockIdx.y;
    int x0 = blockIdx.x*256;
    int tid = threadIdx.x;
    for (int i = tid; i < NCIN*WW; i += 256) Ws[i] = w0[i];
    if (tid < WW) Bs[tid] = b0[tid];
    if (tid < 16) Zs[tid] = z[b*16 + tid];
    __syncthreads();
    int x = x0 + tid;
    const float4* up = (const float4*)(u + ((size_t)b*LL + x)*8);
    float4 a0 = up[0], a1 = up[1];
    float ur[8] = {a0.x,a0.y,a0.z,a0.w,a1.x,a1.y,a1.z,a1.w};
    float zr[16];
    #pragma unroll
    for (int j=0;j<16;j++) zr[j] = Zs[j];
    for (int c=0;c<WW;c++){
        float acc = Bs[c];
        #pragma unroll
        for (int j=0;j<8;j++)  acc += ur[j]*Ws[j*WW+c];
        #pragma unroll
        for (int j=0;j<16;j++) acc += zr[j]*Ws[(8+j)*WW+c];
        split_store(h_hi, h_lo, ((size_t)b*WW + c)*LL + x, acc);
    }
}

// ---------------- truncated DFT: register-only split-bf16 MFMA, split-K ----------------
// part[s][row][n] = sum_{x in split s} h[row][x]*TD[n][x]
// grid (64 row-tiles, 16 splits), 256 threads (4 waves), wave w -> rows rt*64+16w..+15.
__global__ __launch_bounds__(256) void k_dft(
        const unsigned short* __restrict__ h_hi, const unsigned short* __restrict__ h_lo,
        const unsigned short* __restrict__ td_hi, const unsigned short* __restrict__ td_lo,
        float* __restrict__ part){
    int rt = blockIdx.x;
    int s  = blockIdx.y;
    int tid = threadIdx.x;
    int w = tid >> 6;
    int lane = tid & 63;
    int g = lane >> 4;       // k-group
    int i = lane & 15;       // A-row / B-col
    f32x4 acc[4];
    #pragma unroll
    for (int nf=0;nf<4;nf++) acc[nf] = (f32x4){0.f,0.f,0.f,0.f};
    size_t arow = (size_t)(rt*64 + w*16 + i)*LL;
    int xbase = s*256;
    for (int ks=0; ks<8; ks++){
        int xk = xbase + ks*32 + g*8;
        short8 a_hi = *(const short8*)(h_hi + arow + xk);
        short8 a_lo = *(const short8*)(h_lo + arow + xk);
        #pragma unroll
        for (int nf=0;nf<4;nf++){
            size_t brow = (size_t)(nf*16 + i)*LL + xk;
            short8 b_hi = *(const short8*)(td_hi + brow);
            short8 b_lo = *(const short8*)(td_lo + brow);
            acc[nf] = __builtin_amdgcn_mfma_f32_16x16x32_bf16(a_lo, b_hi, acc[nf], 0,0,0);
            acc[nf] = __builtin_amdgcn_mfma_f32_16x16x32_bf16(a_hi, b_lo, acc[nf], 0,0,0);
            acc[nf] = __builtin_amdgcn_mfma_f32_16x16x32_bf16(a_hi, b_hi, acc[nf], 0,0,0);
        }
    }
    // D: row=(lane>>4)*4+r, col=lane&15
    int drow = rt*64 + w*16 + g*4;
    #pragma unroll
    for (int nf=0;nf<4;nf++)
        #pragma unroll
        for (int r=0;r<4;r++)
            part[((size_t)s*4096 + drow + r)*64 + nf*16 + i] = acc[nf][r];
}

// ---------------- reduce partials -> hfT[b][m][{re,im}][i] (fp32) ----------------
__global__ void k_reduce(const float* __restrict__ part, float* __restrict__ hfT){
    int e = blockIdx.x*256 + threadIdx.x;       // < 64*32*128
    int i    = e & 63;
    int reim = (e >> 6) & 1;
    int m    = (e >> 7) & 31;
    int b    = e >> 12;
    int n = m + 32*reim;
    size_t rowoff = ((size_t)b*WW + i)*64 + n;
    float s = 0.f;
    #pragma unroll
    for (int sp=0; sp<NSPLIT; sp++) s += part[(size_t)sp*262144 + rowoff];
    hfT[e] = s;
}

// ---------------- mode mix -> of fp32 [b][o][64] + bf16 planes ----------------
__global__ void k_mix(const float* __restrict__ hfT, const float* __restrict__ wrT,
                      const float* __restrict__ wiT, float* __restrict__ of,
                      unsigned short* __restrict__ of_hi, unsigned short* __restrict__ of_lo){
    int m = blockIdx.x, b = blockIdx.y;
    int o = threadIdx.x;
    __shared__ float hr[64], hi_[64];
    const float* row = hfT + ((size_t)b*NMODES + m)*128;
    hr[o] = row[o];
    hi_[o] = row[64+o];
    __syncthreads();
    float ar = 0.f, ai = 0.f;
    const float* wr = wrT + (size_t)m*4096;   // [i][o]
    const float* wi = wiT + (size_t)m*4096;
    for (int i=0;i<64;i++){
        float wrv = wr[i*64+o], wiv = wi[i*64+o];
        float r = hr[i], im = hi_[i];
        ar += r*wrv - im*wiv;
        ai += r*wiv + im*wrv;
    }
    size_t base = ((size_t)b*WW+o)*64;
    of[base + m]      = ar;
    of[base + 32 + m] = ai;
    split_store(of_hi, of_lo, base + m, ar);
    split_store(of_hi, of_lo, base + 32 + m, ai);
}

// ---------------- fused iDFT + skip + bias + gelu (split-bf16 MFMA) ----------------
// out[o][x] = sum_{k<64} skwT[o][k]*h[b][k][x] + sum_j of[b][o][j]*TI[j][x] + skb[o]
// grid (64 x-tiles, 64 b), 256 threads (4 waves), wave w -> x-cols 16w..16w+15 (local).
__global__ __launch_bounds__(256) void k_fused(
        const unsigned short* __restrict__ h_hi, const unsigned short* __restrict__ h_lo,
        const unsigned short* __restrict__ ti_hi, const unsigned short* __restrict__ ti_lo,
        const unsigned short* __restrict__ skwT_hi, const unsigned short* __restrict__ skwT_lo,
        const unsigned short* __restrict__ of_hi, const unsigned short* __restrict__ of_lo,
        const float* __restrict__ skb,
        unsigned short* __restrict__ ho_hi, unsigned short* __restrict__ ho_lo){
    __shared__ __align__(16) char ldsraw[2*64*PK*2];   // 34816 B; re-used as T (16640 B)
    unsigned short* Bs_hi = (unsigned short*)ldsraw;
    unsigned short* Bs_lo = Bs_hi + 64*PK;
    int b  = blockIdx.y;
    int X0 = blockIdx.x*64;
    int tid = threadIdx.x;
    int xl = tid & 63;
    int kq = tid >> 6;
    // --- stage B tile transposed: BsT[x][k], k = channel(0..63) then TI-row(64..127)
    for (int pl=0; pl<2; pl++){
        const unsigned short* hsrc = pl ? h_lo : h_hi;
        const unsigned short* tsrc = pl ? ti_lo : ti_hi;
        unsigned short* Bs = pl ? Bs_lo : Bs_hi;
        #pragma unroll
        for (int it=0; it<8; it++){
            int k0 = (kq + it*4)*4;          // 0..124, step 4
            const unsigned short* s0 = (k0 < 64)
                ? (hsrc + ((size_t)(b*64 + k0))*LL + X0 + xl)
                : (tsrc + ((size_t)(k0-64))*LL + X0 + xl);
            unsigned short v0 = s0[0], v1 = s0[LL], v2 = s0[2*LL], v3 = s0[3*LL];
            unsigned long long pk = (unsigned long long)v0
                                  | ((unsigned long long)v1<<16)
                                  | ((unsigned long long)v2<<32)
                                  | ((unsigned long long)v3<<48);
            *(unsigned long long*)(Bs + xl*PK + k0) = pk;
        }
    }
    __syncthreads();
    // --- MFMA: M=o(64), N=x(16 per wave), K=128
    int w = tid >> 6, lane = tid & 63, g = lane >> 4, j = lane & 15;
    f32x4 acc[4];
    #pragma unroll
    for (int mf=0; mf<4; mf++) acc[mf] = (f32x4){0.f,0.f,0.f,0.f};
    const unsigned short* BrH = Bs_hi + (w*16 + j)*PK;
    const unsigned short* BrL = Bs_lo + (w*16 + j)*PK;
    #pragma unroll
    for (int ks=0; ks<4; ks++){
        short8 bh = *(const short8*)(BrH + ks*32 + g*8);
        short8 bl = *(const short8*)(BrL + ks*32 + g*8);
        #pragma unroll
        for (int mf=0; mf<4; mf++){
            int o = mf*16 + j;
            const unsigned short *pa_hi, *pa_lo;
            if (ks < 2){
                pa_hi = skwT_hi + (o<<6) + ks*32 + g*8;
                pa_lo = skwT_lo + (o<<6) + ks*32 + g*8;
            } else {
                size_t bo = ((size_t)(b*64 + o))<<6;
                pa_hi = of_hi + bo + (ks-2)*32 + g*8;
                pa_lo = of_lo + bo + (ks-2)*32 + g*8;
            }
            short8 ah = *(const short8*)pa_hi;
            short8 al = *(const short8*)pa_lo;
            acc[mf] = __builtin_amdgcn_mfma_f32_16x16x32_bf16(al, bh, acc[mf], 0,0,0);
            acc[mf] = __builtin_amdgcn_mfma_f32_16x16x32_bf16(ah, bl, acc[mf], 0,0,0);
            acc[mf] = __builtin_amdgcn_mfma_f32_16x16x32_bf16(ah, bh, acc[mf], 0,0,0);
        }
    }
    // --- epilogue: bias + gelu + split -> packed LDS tile -> coalesced store
    __syncthreads();                         // Bs no longer needed
    unsigned int* T = (unsigned int*)ldsraw; // [64 o][65] packed (hi | lo<<16)
    #pragma unroll
    for (int mf=0; mf<4; mf++){
        #pragma unroll
        for (int r=0; r<4; r++){
            int o = mf*16 + g*4 + r;
            float v = acc[mf][r] + skb[o];
            v = gelu_tanh(v);
            unsigned short h16 = bf16_rn(v);
            unsigned short l16 = bf16_rn(v - bf16f(h16));
            T[o*65 + w*16 + j] = (unsigned int)h16 | ((unsigned int)l16 << 16);
        }
    }
    __syncthreads();
    #pragma unroll
    for (int q=0; q<4; q++){
        int f = tid + q*256;
        int o = f >> 4, seg = f & 15;
        const unsigned int* tr = T + o*65 + seg*4;
        unsigned int t0=tr[0], t1=tr[1], t2=tr[2], t3=tr[3];
        unsigned long long hv = (unsigned long long)(t0 & 0xffffu)
            | ((unsigned long long)(t1 & 0xffffu)<<16)
            | ((unsigned long long)(t2 & 0xffffu)<<32)
            | ((unsigned long long)(t3 & 0xffffu)<<48);
        unsigned long long lv = (unsigned long long)(t0 >> 16)
            | ((unsigned long long)(t1 >> 16)<<16)
            | ((unsigned long long)(t2 >> 16)<<32)
            | ((unsigned long long)(t3 >> 16)<<48);
        size_t base = ((size_t)(b*64 + o))*LL + X0 + seg*4;
        *(unsigned long long*)(ho_hi + base) = hv;
        *(unsigned long long*)(ho_lo + base) = lv;
    }
}

// ---------------- final: layer-3 tail at x=L-1 + projection ----------------
__global__ void k_final(const unsigned short* __restrict__ h3_hi,
                        const unsigned short* __restrict__ h3_lo,
                        const float* __restrict__ of,
                        const float* __restrict__ skw, const float* __restrict__ skb,
                        const unsigned short* __restrict__ ti_hi,
                        const unsigned short* __restrict__ ti_lo,
                        const float* __restrict__ w1, const float* __restrict__ b1,
                        const float* __restrict__ w2, const float* __restrict__ b2,
                        float* __restrict__ out){
    int b = blockIdx.x;
    int tid = threadIdx.x;  // 128
    __shared__ float hch[64];
    __shared__ float til[64];
    __shared__ float hv[64];
    __shared__ float qv[128];
    if (tid < 64){
        size_t idx = ((size_t)(b*64 + tid))*LL + (LL-1);
        hch[tid] = bf16f(h3_hi[idx]) + bf16f(h3_lo[idx]);
    } else {
        size_t idx = (size_t)(tid-64)*LL + (LL-1);
        til[tid-64] = bf16f(ti_hi[idx]) + bf16f(ti_lo[idx]);
    }
    __syncthreads();
    if (tid < 64){
        int o = tid;
        float acc = skb[o];
        const float* ofr = of + ((size_t)b*WW + o)*64;
        #pragma unroll
        for (int j=0;j<64;j++) acc += ofr[j]*til[j];
        #pragma unroll
        for (int i=0;i<64;i++) acc += hch[i]*skw[i*64+o];
        hv[o] = acc;                       // last layer: no gelu
    }
    __syncthreads();
    {
        int p = tid;
        float acc = b1[p];
        for (int o=0;o<64;o++) acc += hv[o]*w1[o*NPROJ+p];
        qv[p] = gelu_tanh(acc);
    }
    __syncthreads();
    if (tid < NSTC){
        int s = tid;
        float acc = b2[s];
        for (int p=0;p<NPROJ;p++) acc += qv[p]*w2[p*NSTC+s];
        out[b*NSTC + s] = acc;
    }
}

extern "C" void kernel_launch(void* const* d_in, const int* in_sizes, int n_in,
                              void* d_out, int out_size, void* d_ws, size_t ws_size,
                              hipStream_t stream) {
    const float* u     = (const float*)d_in[0];
    const float* z     = (const float*)d_in[1];
    // d_in[2] = t, unused by reference
    const float* fc0w  = (const float*)d_in[3];
    const float* fc0b  = (const float*)d_in[4];
    const float* swr   = (const float*)d_in[5];
    const float* swi   = (const float*)d_in[6];
    const float* skw   = (const float*)d_in[7];
    const float* skb   = (const float*)d_in[8];
    const float* fc1w  = (const float*)d_in[9];
    const float* fc1b  = (const float*)d_in[10];
    const float* fc2w  = (const float*)d_in[11];
    const float* fc2b  = (const float*)d_in[12];
    float* out = (float*)d_out;

    const size_t SZ_HP   = (size_t)4096*LL*2;           // 32 MiB per h plane
    const size_t SZ_TBL  = (size_t)64*LL*2;             // 512 KiB per table plane
    const size_t SZ_HFT  = (size_t)64*32*128*4;         // 1 MiB
    const size_t SZ_OF   = (size_t)64*64*64*4;          // 1 MiB fp32
    const size_t SZ_OFP  = (size_t)64*64*64*2;          // 512 KiB per of plane
    const size_t SZ_WT   = (size_t)NLAY*NMODES*WW*WW*4; // 2 MiB
    const size_t SZ_SKT  = (size_t)NLAY*WW*WW*2;        // 32 KiB per skwT plane

    size_t need = 4*SZ_HP + 4*SZ_TBL + SZ_HFT + SZ_OF + 2*SZ_OFP + 2*SZ_WT + 2*SZ_SKT;
    if (ws_size < need) return;

    char* p = (char*)d_ws;
    unsigned short* hA_hi = (unsigned short*)p; p += SZ_HP;
    unsigned short* hA_lo = (unsigned short*)p; p += SZ_HP;
    unsigned short* hB_hi = (unsigned short*)p; p += SZ_HP;
    unsigned short* hB_lo = (unsigned short*)p; p += SZ_HP;
    unsigned short* TD_hi = (unsigned short*)p; p += SZ_TBL;
    unsigned short* TD_lo = (unsigned short*)p; p += SZ_TBL;
    unsigned short* TI_hi = (unsigned short*)p; p += SZ_TBL;
    unsigned short* TI_lo = (unsigned short*)p; p += SZ_TBL;
    float* hfT   = (float*)p; p += SZ_HFT;
    float* of    = (float*)p; p += SZ_OF;
    unsigned short* of_hi = (unsigned short*)p; p += SZ_OFP;
    unsigned short* of_lo = (unsigned short*)p; p += SZ_OFP;
    float* wrT   = (float*)p; p += SZ_WT;
    float* wiT   = (float*)p; p += SZ_WT;
    unsigned short* skwT_hi = (unsigned short*)p; p += SZ_SKT;
    unsigned short* skwT_lo = (unsigned short*)p; p += SZ_SKT;

    k_tables<<<(LL*NMODES+255)/256, 256, 0, stream>>>(TD_hi, TD_lo, TI_hi, TI_lo);
    k_wt<<<(NLAY*WW*WW*NMODES+255)/256, 256, 0, stream>>>(swr, swi, wrT, wiT,
                                                          skw, skwT_hi, skwT_lo);
    k_lift<<<dim3(LL/256, NB), 256, 0, stream>>>(u, z, fc0w, fc0b, hA_hi, hA_lo);

    unsigned short* cur_hi = hA_hi; unsigned short* cur_lo = hA_lo;
    unsigned short* nxt_hi = hB_hi; unsigned short* nxt_lo = hB_lo;
    for (int l = 0; l < NLAY; l++){
        // part (16 MiB) aliases the dead destination plane (32 MiB)
        float* part = (float*)nxt_hi;
        k_dft<<<dim3(64, NSPLIT), 256, 0, stream>>>(cur_hi, cur_lo, TD_hi, TD_lo, part);
        k_reduce<<<(64*32*128)/256, 256, 0, stream>>>(part, hfT);
        k_mix<<<dim3(NMODES, NB), 64, 0, stream>>>(hfT, wrT + (size_t)l*NMODES*WW*WW,
                                                   wiT + (size_t)l*NMODES*WW*WW,
                                                   of, of_hi, of_lo);
        if (l < NLAY-1){
            k_fused<<<dim3(LL/64, NB), 256, 0, stream>>>(cur_hi, cur_lo, TI_hi, TI_lo,
                skwT_hi + (size_t)l*WW*WW, skwT_lo + (size_t)l*WW*WW,
                of_hi, of_lo, skb + (size_t)l*WW, nxt_hi, nxt_lo);
            unsigned short* t;
            t = cur_hi; cur_hi = nxt_hi; nxt_hi = t;
            t = cur_lo; cur_lo = nxt_lo; nxt_lo = t;
        }
    }
    k_final<<<NB, 128, 0, stream>>>(cur_hi, cur_lo, of, skw + (size_t)3*WW*WW,
                                    skb + (size_t)3*WW, TI_hi, TI_lo,
                                    fc1w, fc1b, fc2w, fc2b, out);
}